// Round 6
// baseline (501.938 us; speedup 1.0000x reference)
//
#include <hip/hip_runtime.h>

// Internal pipeline bf16 (ushort bits); external inputs/outputs float32.
typedef __attribute__((ext_vector_type(8))) short bf16x8;
typedef __attribute__((ext_vector_type(4))) float f32x4;

__device__ __forceinline__ float b2f(ushort b) {
    union { unsigned int u; float f; } x;
    x.u = ((unsigned int)b) << 16;
    return x.f;
}
__device__ __forceinline__ ushort f2b(float f) {
    union { float f; unsigned int u; } x;
    x.f = f;
    unsigned int r = x.u + 0x7fffu + ((x.u >> 16) & 1u);
    return (ushort)(r >> 16);
}
__device__ __forceinline__ int4 pack8(float4 a, float4 b) {
    union { int4 v; ushort u[8]; } r;
    r.u[0] = f2b(a.x); r.u[1] = f2b(a.y); r.u[2] = f2b(a.z); r.u[3] = f2b(a.w);
    r.u[4] = f2b(b.x); r.u[5] = f2b(b.y); r.u[6] = f2b(b.z); r.u[7] = f2b(b.w);
    return r.v;
}
__device__ __forceinline__ int4 add_resb(int4 cs, int4 rs) {
    const ushort* c = (const ushort*)&cs; const ushort* r = (const ushort*)&rs;
    union { int4 v; ushort u[8]; } o;
#pragma unroll
    for (int j = 0; j < 8; j++) o.u[j] = f2b(b2f(c[j]) + b2f(r[j]));
    return o.v;
}
__device__ __forceinline__ int4 add_resf(int4 cs, float4 r0, float4 r1) {
    const ushort* c = (const ushort*)&cs;
    const float* rf0 = (const float*)&r0; const float* rf1 = (const float*)&r1;
    union { int4 v; ushort u[8]; } o;
#pragma unroll
    for (int j = 0; j < 4; j++) o.u[j] = f2b(b2f(c[j]) + rf0[j]);
#pragma unroll
    for (int j = 0; j < 4; j++) o.u[4 + j] = f2b(b2f(c[4 + j]) + rf1[j]);
    return o.v;
}

// Async global->LDS, 16B per lane (wave writes lds_base + lane*16).
__device__ __forceinline__ void gll16(const ushort* g, ushort* l) {
    __builtin_amdgcn_global_load_lds(
        (__attribute__((address_space(1))) void*)(g),
        (__attribute__((address_space(3))) void*)(l), 16, 0, 0);
}

// ---------------------------------------------------------------------------
// B-stationary GEMM, pooled-latency design. Block = 64 cols x 128 rows
// (4 waves x 32 rows). Per 384-K chunk: issue B panel (12 global_load_lds)
// AND the wave's full-K A fragments (24 named-register loads, bf16x8 a[12][2])
// back-to-back, then ONE __syncthreads whose vmcnt(0) drain lands everything
// in a single overlapped latency pool. Hot loop is pure LDS-read + MFMA with
// zero global dependency. The barrier's memory fence pins all loads above it
// and each a[kk][mi] has a distinct use after -> the ~96 A-VGPRs cannot be
// compressed away (R5's failure mode). 48KB LDS -> 3 blocks/CU; VGPR ~165 ->
// 3 waves/SIMD via __launch_bounds__(256,2).
// ---------------------------------------------------------------------------
__global__ __launch_bounds__(256, 2) void gemm_bs(
    const ushort* __restrict__ A, const ushort* __restrict__ Bt,
    ushort* __restrict__ C, const float* __restrict__ bias,
    const ushort* __restrict__ resb, const float* __restrict__ resf,
    int N, int K, int relu)
{
    __shared__ __align__(16) ushort sm[24576];     // B panel 64x384 = 48KB
    const int tid  = threadIdx.x;
    const int wave = tid >> 6, lane = tid & 63;
    const int qd = lane >> 4, lc = lane & 15;
    const int id = blockIdx.x, xcd = id & 7, sub = id >> 3;
    const int mc = sub & 15, ct = sub >> 4;        // 16 row-chunks per XCD
    const int row0 = (xcd * 16 + mc) * 128;
    const int col0 = ct * 64;

    f32x4 acc[2][4];
#pragma unroll
    for (int i = 0; i < 2; i++)
#pragma unroll
        for (int j = 0; j < 4; j++) acc[i][j] = 0.0f;

    const ushort* Aw = A + (size_t)(row0 + wave * 32 + lc) * K + qd * 8;
    const ushort* Bw = Bt + (size_t)(col0 + wave * 16 + (lane >> 2)) * K + (lane & 3) * 8;
    ushort* Bsw = &sm[wave * 512];

    const int NKC = K / 384;
    for (int kc = 0; kc < NKC; ++kc) {
        if (kc) __syncthreads();                   // done reading prev B chunk
        // Issue the whole chunk's loads back-to-back: 12 B->LDS + 24 A->VGPR.
#pragma unroll
        for (int j = 0; j < 12; j++)
            gll16(Bw + kc * 384 + j * 32, Bsw + j * 2048);
        const ushort* Akc = Aw + kc * 384;
        bf16x8 a[12][2];                           // full-K A prefetch (96 VGPR)
#pragma unroll
        for (int kk = 0; kk < 12; kk++)
#pragma unroll
            for (int mi = 0; mi < 2; mi++)
                a[kk][mi] = *(const bf16x8*)(Akc + (size_t)mi * 16 * K + kk * 32);
        __syncthreads();                           // ONE pooled latency drain

        // Hot loop: pure LDS + MFMA, no global deps.
#pragma unroll
        for (int kk = 0; kk < 12; ++kk) {
            bf16x8 bfr[4];
#pragma unroll
            for (int ni = 0; ni < 4; ni++)
                bfr[ni] = *(const bf16x8*)&sm[kk * 2048 + (ni * 16 + lc) * 32 + qd * 8];
            __builtin_amdgcn_s_setprio(1);
#pragma unroll
            for (int mi = 0; mi < 2; mi++)
#pragma unroll
                for (int ni = 0; ni < 4; ni++)
                    acc[mi][ni] = __builtin_amdgcn_mfma_f32_16x16x32_bf16(
                        a[kk][mi], bfr[ni], acc[mi][ni], 0, 0, 0);
            __builtin_amdgcn_s_setprio(0);
        }
    }

    // Epilogue: per-wave region of Cs (overlays Bs), coalesced b128 stores.
    __syncthreads();                               // all waves done with Bs
    ushort* Csw = &sm[wave * 32 * 68];
#pragma unroll
    for (int mi = 0; mi < 2; mi++)
#pragma unroll
        for (int r = 0; r < 4; r++) {
            int lr = mi * 16 + qd * 4 + r;
#pragma unroll
            for (int ni = 0; ni < 4; ni++) {
                float v = acc[mi][ni][r];
                if (bias) v += bias[col0 + ni * 16 + lc];
                if (relu) v = fmaxf(v, 0.0f);
                Csw[lr * 68 + ni * 16 + lc] = f2b(v);
            }
        }
    asm volatile("s_waitcnt lgkmcnt(0)" ::: "memory");  // wave-private region
    const int rowW = row0 + wave * 32;
#pragma unroll
    for (int p = 0; p < 4; p++) {
        int lr = p * 8 + (lane >> 3), cc = (lane & 7) * 8;
        size_t base = (size_t)(rowW + lr) * N + col0 + cc;
        int4 d = *(const int4*)&Csw[lr * 68 + cc];
        if (resb) d = add_resb(d, *(const int4*)&resb[base]);
        else if (resf) d = add_resf(d, *(const float4*)&resf[base],
                                       *(const float4*)&resf[base + 4]);
        *(int4*)&C[base] = d;
    }
}

// ---------------------------------------------------------------------------
// Fused q2 + kv2 (both K=384), same pooled-latency structure.
// col tiles 0..5 -> C1(N=384), 6..17 -> C2(N=768). Grid 8*16*18 = 2304.
// ---------------------------------------------------------------------------
__global__ __launch_bounds__(256, 2) void gemm_bs_dual(
    const ushort* __restrict__ A1, const ushort* __restrict__ B1t,
    ushort* __restrict__ C1, const float* __restrict__ bias1, int N1,
    const ushort* __restrict__ A2, const ushort* __restrict__ B2t,
    ushort* __restrict__ C2, const float* __restrict__ bias2, int N2,
    int split)
{
    __shared__ __align__(16) ushort sm[24576];
    const int K = 384;
    const int tid  = threadIdx.x;
    const int wave = tid >> 6, lane = tid & 63;
    const int qd = lane >> 4, lc = lane & 15;
    const int id = blockIdx.x, xcd = id & 7, sub = id >> 3;
    const int mc = sub & 15, ct = sub >> 4;
    const int row0 = (xcd * 16 + mc) * 128;
    const bool first = ct < split;
    const ushort* A  = first ? A1 : A2;
    const ushort* Bt = first ? B1t : B2t;
    ushort* C        = first ? C1 : C2;
    const float* bias = first ? bias1 : bias2;
    const int N      = first ? N1 : N2;
    const int col0   = (first ? ct : ct - split) * 64;

    f32x4 acc[2][4];
#pragma unroll
    for (int i = 0; i < 2; i++)
#pragma unroll
        for (int j = 0; j < 4; j++) acc[i][j] = 0.0f;

    const ushort* Aw = A + (size_t)(row0 + wave * 32 + lc) * K + qd * 8;
    const ushort* Bw = Bt + (size_t)(col0 + wave * 16 + (lane >> 2)) * K + (lane & 3) * 8;
    ushort* Bsw = &sm[wave * 512];

#pragma unroll
    for (int j = 0; j < 12; j++)
        gll16(Bw + j * 32, Bsw + j * 2048);
    bf16x8 a[12][2];
#pragma unroll
    for (int kk = 0; kk < 12; kk++)
#pragma unroll
        for (int mi = 0; mi < 2; mi++)
            a[kk][mi] = *(const bf16x8*)(Aw + (size_t)mi * 16 * K + kk * 32);
    __syncthreads();

#pragma unroll
    for (int kk = 0; kk < 12; ++kk) {
        bf16x8 bfr[4];
#pragma unroll
        for (int ni = 0; ni < 4; ni++)
            bfr[ni] = *(const bf16x8*)&sm[kk * 2048 + (ni * 16 + lc) * 32 + qd * 8];
        __builtin_amdgcn_s_setprio(1);
#pragma unroll
        for (int mi = 0; mi < 2; mi++)
#pragma unroll
            for (int ni = 0; ni < 4; ni++)
                acc[mi][ni] = __builtin_amdgcn_mfma_f32_16x16x32_bf16(
                    a[kk][mi], bfr[ni], acc[mi][ni], 0, 0, 0);
        __builtin_amdgcn_s_setprio(0);
    }

    __syncthreads();
    ushort* Csw = &sm[wave * 32 * 68];
#pragma unroll
    for (int mi = 0; mi < 2; mi++)
#pragma unroll
        for (int r = 0; r < 4; r++) {
            int lr = mi * 16 + qd * 4 + r;
#pragma unroll
            for (int ni = 0; ni < 4; ni++)
                Csw[lr * 68 + ni * 16 + lc] = f2b(acc[mi][ni][r] + bias[col0 + ni * 16 + lc]);
        }
    asm volatile("s_waitcnt lgkmcnt(0)" ::: "memory");
    const int rowW = row0 + wave * 32;
#pragma unroll
    for (int p = 0; p < 4; p++) {
        int lr = p * 8 + (lane >> 3), cc = (lane & 7) * 8;
        size_t base = (size_t)(rowW + lr) * N + col0 + cc;
        *(int4*)&C[base] = *(const int4*)&Csw[lr * 68 + cc];
    }
}

// ---------------------------------------------------------------------------
// Attention: one block per (b, h, 64-row q tile). Causal tril + softmax.
// ---------------------------------------------------------------------------
__global__ __launch_bounds__(256) void attn(
    const ushort* __restrict__ q, int qstr,
    const ushort* __restrict__ k, int kstr,
    const ushort* __restrict__ v, int vstr,
    ushort* __restrict__ out)
{
    __shared__ __align__(16) ushort Qs[64 * 72];
    __shared__ __align__(16) ushort Kc[64 * 72];
    __shared__ __align__(16) ushort Vc[64 * 72];
    __shared__ __align__(16) ushort Ps[64 * 264];

    const int tid = threadIdx.x;
    const int wave = tid >> 6, lane = tid & 63;
    const int qd = lane >> 4, lc = lane & 15;
    const int b = blockIdx.z, h = blockIdx.y, t0 = blockIdx.x * 64;
    const int hc = h * 64;
    const float scale = 0.051031036307982884f;  // 384^-0.5 (faithful: E, not HS)

    {
        int r = tid >> 2, c = (tid & 3) * 16;
        int4 q0 = *(const int4*)&q[(size_t)(b * 256 + t0 + r) * qstr + hc + c];
        int4 q1 = *(const int4*)&q[(size_t)(b * 256 + t0 + r) * qstr + hc + c + 8];
        *(int4*)&Qs[r * 72 + c] = q0;
        *(int4*)&Qs[r * 72 + c + 8] = q1;
    }

    f32x4 accS[16];
#pragma unroll
    for (int j = 0; j < 16; j++) accS[j] = 0.0f;

    for (int uc = 0; uc < 4; uc++) {
        int r = tid >> 2, c = (tid & 3) * 16;
        int4 k0v = *(const int4*)&k[(size_t)(b * 256 + uc * 64 + r) * kstr + hc + c];
        int4 k1v = *(const int4*)&k[(size_t)(b * 256 + uc * 64 + r) * kstr + hc + c + 8];
        __syncthreads();
        *(int4*)&Kc[r * 72 + c] = k0v;
        *(int4*)&Kc[r * 72 + c + 8] = k1v;
        __syncthreads();
#pragma unroll
        for (int s0 = 0; s0 < 64; s0 += 32) {
            bf16x8 a = *(const bf16x8*)&Qs[(wave * 16 + lc) * 72 + s0 + qd * 8];
#pragma unroll
            for (int ni = 0; ni < 4; ni++) {
                bf16x8 bb = *(const bf16x8*)&Kc[(ni * 16 + lc) * 72 + s0 + qd * 8];
                accS[uc * 4 + ni] =
                    __builtin_amdgcn_mfma_f32_16x16x32_bf16(a, bb, accS[uc * 4 + ni], 0, 0, 0);
            }
        }
    }

#pragma unroll
    for (int rr = 0; rr < 4; rr++) {
        int t = t0 + wave * 16 + qd * 4 + rr;
        float pv[16];
        float mx = -3.0e38f;
#pragma unroll
        for (int j = 0; j < 16; j++) {
            int u = (j >> 2) * 64 + (j & 3) * 16 + lc;
            float s = accS[j][rr] * scale;
            s = (u <= t) ? s : -3.0e38f;
            pv[j] = s;
            mx = fmaxf(mx, s);
        }
#pragma unroll
        for (int m = 1; m < 16; m <<= 1) mx = fmaxf(mx, __shfl_xor(mx, m, 16));
        float sum = 0.0f;
#pragma unroll
        for (int j = 0; j < 16; j++) { float p = __expf(pv[j] - mx); pv[j] = p; sum += p; }
#pragma unroll
        for (int m = 1; m < 16; m <<= 1) sum += __shfl_xor(sum, m, 16);
        float inv = 1.0f / sum;
#pragma unroll
        for (int j = 0; j < 16; j++) {
            int u = (j >> 2) * 64 + (j & 3) * 16 + lc;
            Ps[(wave * 16 + qd * 4 + rr) * 264 + u] = f2b(pv[j] * inv);
        }
    }

    f32x4 accO[4];
#pragma unroll
    for (int j = 0; j < 4; j++) accO[j] = 0.0f;
    for (int uc = 0; uc < 4; uc++) {
        int r = tid >> 2, s0 = (tid & 3) * 16;
        int4 v0 = *(const int4*)&v[(size_t)(b * 256 + uc * 64 + r) * vstr + hc + s0];
        int4 v1 = *(const int4*)&v[(size_t)(b * 256 + uc * 64 + r) * vstr + hc + s0 + 8];
        __syncthreads();
        {
            const ushort* t0p = (const ushort*)&v0;
            const ushort* t1p = (const ushort*)&v1;
#pragma unroll
            for (int j = 0; j < 8; j++) Vc[(s0 + j) * 72 + r] = t0p[j];
#pragma unroll
            for (int j = 0; j < 8; j++) Vc[(s0 + 8 + j) * 72 + r] = t1p[j];
        }
        __syncthreads();
#pragma unroll
        for (int u0 = 0; u0 < 64; u0 += 32) {
            bf16x8 a = *(const bf16x8*)&Ps[(wave * 16 + lc) * 264 + uc * 64 + u0 + qd * 8];
#pragma unroll
            for (int ni = 0; ni < 4; ni++) {
                bf16x8 bb = *(const bf16x8*)&Vc[(ni * 16 + lc) * 72 + u0 + qd * 8];
                accO[ni] = __builtin_amdgcn_mfma_f32_16x16x32_bf16(a, bb, accO[ni], 0, 0, 0);
            }
        }
    }

#pragma unroll
    for (int ni = 0; ni < 4; ni++)
#pragma unroll
        for (int rr = 0; rr < 4; rr++) {
            int t = t0 + wave * 16 + qd * 4 + rr;
            out[(size_t)(b * 256 + t) * 384 + hc + ni * 16 + lc] = f2b(accO[ni][rr]);
        }
}

// ---------------------------------------------------------------------------
// LayerNorm rows of 384. One wave per row. g/be f32; in bf16; out bf16 or f32.
// ---------------------------------------------------------------------------
__global__ __launch_bounds__(256) void lnorm(
    const ushort* __restrict__ in, const float* __restrict__ g,
    const float* __restrict__ be, ushort* __restrict__ outb,
    float* __restrict__ outf)
{
    const int wave = threadIdx.x >> 6, lane = threadIdx.x & 63;
    const int row = blockIdx.x * 4 + wave;
    const ushort* r = in + (size_t)row * 384;
    float x[6], s1 = 0.0f, s2 = 0.0f;
#pragma unroll
    for (int j = 0; j < 6; j++) {
        x[j] = b2f(r[j * 64 + lane]);
        s1 += x[j]; s2 += x[j] * x[j];
    }
#pragma unroll
    for (int m = 1; m < 64; m <<= 1) {
        s1 += __shfl_xor(s1, m, 64);
        s2 += __shfl_xor(s2, m, 64);
    }
    float mean = s1 * (1.0f / 384.0f);
    float var  = s2 * (1.0f / 384.0f) - mean * mean;
    float rstd = rsqrtf(var + 1e-5f);
#pragma unroll
    for (int j = 0; j < 6; j++) {
        float y = (x[j] - mean) * rstd * g[j * 64 + lane] + be[j * 64 + lane];
        if (outb) outb[(size_t)row * 384 + j * 64 + lane] = f2b(y);
        if (outf) outf[(size_t)row * 384 + j * 64 + lane] = y;
    }
}

// ---------------------------------------------------------------------------
// Fused prep (unchanged).
// ---------------------------------------------------------------------------
__device__ __forceinline__ void dev_cvt(const float* in, ushort* out, int blk) {
    size_t i = ((size_t)blk * 256 + threadIdx.x) * 8;
    float4 a = *(const float4*)(in + i);
    float4 b = *(const float4*)(in + i + 4);
    *(int4*)(out + i) = pack8(a, b);
}
__device__ __forceinline__ void dev_transp(const float* in, ushort* out,
                                           int R, int C, int bx, int by,
                                           float (*t)[33]) {
    const int tx = threadIdx.x & 31, ty = threadIdx.x >> 5;
    const int c0 = bx * 32, r0 = by * 32;
#pragma unroll
    for (int i = 0; i < 32; i += 8)
        t[ty + i][tx] = in[(size_t)(r0 + ty + i) * C + c0 + tx];
    __syncthreads();
#pragma unroll
    for (int i = 0; i < 32; i += 8)
        out[(size_t)(c0 + ty + i) * R + r0 + tx] = f2b(t[tx][ty + i]);
}
__device__ __forceinline__ void dev_packqkv(const float* wq, const float* wk,
                                            const float* wv, ushort* Wt,
                                            int blk, float (*t)[33]) {
    const int tx = threadIdx.x & 31, ty = threadIdx.x >> 5;
    const int bx = blk % 12, by = (blk / 12) % 2, bz = blk / 24;
    const int e0 = bx * 32, s0 = by * 32;
    const int seg = bz / 6, h = bz - seg * 6;
    const float* w = (seg == 0) ? wq : (seg == 1) ? wk : wv;
    const float* wh = w + (size_t)h * 384 * 64;
#pragma unroll
    for (int i = 0; i < 32; i += 8)
        t[ty + i][tx] = wh[(size_t)(e0 + ty + i) * 64 + s0 + tx];
    __syncthreads();
    const int nbase = seg * 384 + h * 64 + s0;
#pragma unroll
    for (int i = 0; i < 32; i += 8)
        Wt[(size_t)(nbase + ty + i) * 384 + e0 + tx] = f2b(t[tx][ty + i]);
}

__global__ __launch_bounds__(256) void prep_all(
    const float* __restrict__ x, ushort* __restrict__ xb,
    const float* __restrict__ enc, ushort* __restrict__ encb,
    const float* __restrict__ s1wq, const float* __restrict__ s1wk,
    const float* __restrict__ s1wv, ushort* __restrict__ W1,
    const float* __restrict__ s2wq, const float* __restrict__ s2wk,
    const float* __restrict__ s2wv, ushort* __restrict__ W2,
    const float* __restrict__ s1pw, ushort* __restrict__ pw1t,
    const float* __restrict__ s2pw, ushort* __restrict__ pw2t,
    const float* __restrict__ fw1, ushort* __restrict__ w1t,
    const float* __restrict__ fw2, ushort* __restrict__ w2t,
    const float* __restrict__ s1bq, const float* __restrict__ s1bk,
    const float* __restrict__ s1bv, const float* __restrict__ s2bq,
    const float* __restrict__ s2bk, const float* __restrict__ s2bv,
    float* __restrict__ bias1, float* __restrict__ bias2)
{
    __shared__ float t[32][33];
    int blk = blockIdx.x;
    if (blk < 3072) { dev_cvt(x, xb, blk); return; }
    blk -= 3072;
    if (blk < 3072) { dev_cvt(enc, encb, blk); return; }
    blk -= 3072;
    if (blk < 432) { dev_packqkv(s1wq, s1wk, s1wv, W1, blk, t); return; }
    blk -= 432;
    if (blk < 432) { dev_packqkv(s2wq, s2wk, s2wv, W2, blk, t); return; }
    blk -= 432;
    if (blk < 144) { dev_transp(s1pw, pw1t, 384, 384, blk % 12, blk / 12, t); return; }
    blk -= 144;
    if (blk < 144) { dev_transp(s2pw, pw2t, 384, 384, blk % 12, blk / 12, t); return; }
    blk -= 144;
    if (blk < 576) { dev_transp(fw1, w1t, 384, 1536, blk % 48, blk / 48, t); return; }
    blk -= 576;
    if (blk < 576) { dev_transp(fw2, w2t, 1536, 384, blk % 12, blk / 12, t); return; }
    blk -= 576;
    int i = blk * 256 + threadIdx.x;
    if (i >= 2304) return;
    int grp = i / 1152, r = i - grp * 1152;
    int seg = r / 384, nn = r - seg * 384;
    const float* src = grp == 0 ? (seg == 0 ? s1bq : seg == 1 ? s1bk : s1bv)
                                : (seg == 0 ? s2bq : seg == 1 ? s2bk : s2bv);
    (grp == 0 ? bias1 : bias2)[r] = src[nn];
}

// ---------------------------------------------------------------------------
extern "C" void kernel_launch(void* const* d_in, const int* in_sizes, int n_in,
                              void* d_out, int out_size, void* d_ws, size_t ws_size,
                              hipStream_t stream)
{
    const float* enc = (const float*)d_in[0];
    const float* x   = (const float*)d_in[1];
    const float* s1wq = (const float*)d_in[2];  const float* s1bq = (const float*)d_in[3];
    const float* s1wk = (const float*)d_in[4];  const float* s1bk = (const float*)d_in[5];
    const float* s1wv = (const float*)d_in[6];  const float* s1bv = (const float*)d_in[7];
    const float* s1pw = (const float*)d_in[8];  const float* s1pb = (const float*)d_in[9];
    const float* s2wq = (const float*)d_in[10]; const float* s2bq = (const float*)d_in[11];
    const float* s2wk = (const float*)d_in[12]; const float* s2bk = (const float*)d_in[13];
    const float* s2wv = (const float*)d_in[14]; const float* s2bv = (const float*)d_in[15];
    const float* s2pw = (const float*)d_in[16]; const float* s2pb = (const float*)d_in[17];
    const float* fw1 = (const float*)d_in[18];  const float* fb1 = (const float*)d_in[19];
    const float* fw2 = (const float*)d_in[20];  const float* fb2 = (const float*)d_in[21];
    const float* g1 = (const float*)d_in[22];   const float* be1 = (const float*)d_in[23];
    const float* g2 = (const float*)d_in[24];   const float* be2 = (const float*)d_in[25];
    const float* g3 = (const float*)d_in[26];   const float* be3 = (const float*)d_in[27];

    if (ws_size < 80216064u) return;  // proven-available scratch size

    ushort* wsp = (ushort*)d_ws;           // ushort-element offsets
    ushort* qkv1 = wsp;
    ushort* q2   = wsp;
    ushort* kv2  = wsp + 6291456;
    ushort* h1   = wsp;
    ushort* att  = wsp + 18874368;         // [16384,384]; xb shares (dead before attn1)
    ushort* xb   = wsp + 18874368;
    ushort* tmp  = wsp + 25165824;         // [16384,384] pre-LN
    ushort* o1b  = wsp + 31457280;         // [16384,384]
    ushort* W1   = wsp + 37748736;         // [1152,384]
    ushort* W2   = W1 + 442368;
    ushort* pw1t = W2 + 442368;            // [384,384]
    ushort* pw2t = pw1t + 147456;          // [384,384]
    ushort* w1t  = pw2t + 147456;          // [1536,384]
    ushort* w2t  = w1t + 589824;           // [384,1536]

    ushort* encb = (ushort*)d_out;         // dead after kv2 gemm
    ushort* o2b  = (ushort*)d_out;
    float* bias1 = (float*)((ushort*)d_out + 6291456);
    float* bias2 = bias1 + 1152;

    // fused prep (1 dispatch)
    prep_all<<<dim3(8457), dim3(256), 0, stream>>>(
        x, xb, enc, encb,
        s1wq, s1wk, s1wv, W1, s2wq, s2wk, s2wv, W2,
        s1pw, pw1t, s2pw, pw2t, fw1, w1t, fw2, w2t,
        s1bq, s1bk, s1bv, s2bq, s2bk, s2bv, bias1, bias2);

    // stage 1: qkv (8*16*18=2304), attn, proj (8*16*6=768), ln
    gemm_bs<<<dim3(2304), dim3(256), 0, stream>>>(
        xb, W1, qkv1, bias1, nullptr, nullptr, 1152, 384, 0);
    attn<<<dim3(4, 6, 64), dim3(256), 0, stream>>>(
        qkv1, 1152, qkv1 + 384, 1152, qkv1 + 768, 1152, att);
    gemm_bs<<<dim3(768), dim3(256), 0, stream>>>(
        att, pw1t, tmp, s1pb, nullptr, x, 384, 384, 0);
    lnorm<<<dim3(4096), dim3(256), 0, stream>>>(tmp, g1, be1, o1b, nullptr);

    // stage 2 (q2 + kv2 fused: 8*16*18=2304)
    gemm_bs_dual<<<dim3(2304), dim3(256), 0, stream>>>(
        o1b, W2, q2, bias2, 384,
        encb, W2 + 147456, kv2, bias2 + 384, 768, 6);
    attn<<<dim3(4, 6, 64), dim3(256), 0, stream>>>(
        q2, 384, kv2, 768, kv2 + 384, 768, att);
    gemm_bs<<<dim3(768), dim3(256), 0, stream>>>(
        att, pw2t, tmp, s2pb, o1b, nullptr, 384, 384, 0);
    lnorm<<<dim3(4096), dim3(256), 0, stream>>>(tmp, g2, be2, o2b, nullptr);

    // stage 3: ffn1 (8*16*24=3072), ffn2 (8*16*6=768, K=1536 -> 4 chunks)
    gemm_bs<<<dim3(3072), dim3(256), 0, stream>>>(
        o2b, w1t, h1, fb1, nullptr, nullptr, 1536, 384, 1);
    gemm_bs<<<dim3(768), dim3(256), 0, stream>>>(
        h1, w2t, tmp, fb2, o2b, nullptr, 384, 1536, 0);
    lnorm<<<dim3(4096), dim3(256), 0, stream>>>(tmp, g3, be3, nullptr, (float*)d_out);
}

// Round 8
// 482.993 us; speedup vs baseline: 1.0392x; 1.0392x over previous
//
#include <hip/hip_runtime.h>

// Internal pipeline bf16 (ushort bits); external inputs/outputs float32.
typedef __attribute__((ext_vector_type(8))) short bf16x8;
typedef __attribute__((ext_vector_type(4))) float f32x4;
typedef __attribute__((ext_vector_type(4))) int i32x4;

__device__ __forceinline__ float b2f(ushort b) {
    union { unsigned int u; float f; } x;
    x.u = ((unsigned int)b) << 16;
    return x.f;
}
__device__ __forceinline__ ushort f2b(float f) {
    union { float f; unsigned int u; } x;
    x.f = f;
    unsigned int r = x.u + 0x7fffu + ((x.u >> 16) & 1u);
    return (ushort)(r >> 16);
}
__device__ __forceinline__ int4 pack8(float4 a, float4 b) {
    union { int4 v; ushort u[8]; } r;
    r.u[0] = f2b(a.x); r.u[1] = f2b(a.y); r.u[2] = f2b(a.z); r.u[3] = f2b(a.w);
    r.u[4] = f2b(b.x); r.u[5] = f2b(b.y); r.u[6] = f2b(b.z); r.u[7] = f2b(b.w);
    return r.v;
}
// cs + resb (both bf16x8 as i32x4) -> bf16x8
__device__ __forceinline__ i32x4 add_resb(i32x4 cs, i32x4 rs) {
    const ushort* c = (const ushort*)&cs; const ushort* r = (const ushort*)&rs;
    union { i32x4 v; ushort u[8]; } o;
#pragma unroll
    for (int j = 0; j < 8; j++) o.u[j] = f2b(b2f(c[j]) + b2f(r[j]));
    return o.v;
}
__device__ __forceinline__ i32x4 add_resf(i32x4 cs, f32x4 r0, f32x4 r1) {
    const ushort* c = (const ushort*)&cs;
    union { i32x4 v; ushort u[8]; } o;
#pragma unroll
    for (int j = 0; j < 4; j++) o.u[j] = f2b(b2f(c[j]) + r0[j]);
#pragma unroll
    for (int j = 0; j < 4; j++) o.u[4 + j] = f2b(b2f(c[4 + j]) + r1[j]);
    return o.v;
}

// Async global->LDS, 16B per lane (wave writes lds_base + lane*16).
__device__ __forceinline__ void gll16(const ushort* g, ushort* l) {
    __builtin_amdgcn_global_load_lds(
        (__attribute__((address_space(1))) void*)(g),
        (__attribute__((address_space(3))) void*)(l), 16, 0, 0);
}

// ---------------------------------------------------------------------------
// B-stationary GEMM (R4 structure, best measured). Block = 64 cols x
// (4 waves * MI*16 rows). B panel for a 384-K chunk staged ONCE into LDS;
// waves then run independent: per kk = {MI A-frag global loads || 4 ds_read
// || MFMA}, no barriers in hot loop. R7: C-stores and residual loads are
// NON-TEMPORAL (no L2 allocate) so the streaming output cannot evict the
// A working set from the XCD's L2 (A has 18-24x reuse across col-tiles; C and
// residuals have none). XCD swizzle pins A row-chunks to one XCD's L2.
// ---------------------------------------------------------------------------
template<int MI>
__global__ __launch_bounds__(256) void gemm_bs(
    const ushort* __restrict__ A, const ushort* __restrict__ Bt,
    ushort* __restrict__ C, const float* __restrict__ bias,
    const ushort* __restrict__ resb, const float* __restrict__ resf,
    int N, int K, int relu)
{
    __shared__ __align__(16) ushort sm[24576];     // B chunk 64x384 = 48KB
    constexpr int CHUNK = MI * 64;                 // rows per block
    constexpr int PERX  = (16384 / CHUNK) / 8;     // row-chunks per XCD
    const int tid  = threadIdx.x;
    const int wave = tid >> 6, lane = tid & 63;
    const int qd = lane >> 4, lc = lane & 15;
    const int id = blockIdx.x, xcd = id & 7, sub = id >> 3;
    const int mc = sub % PERX, ct = sub / PERX;
    const int row0 = (xcd * PERX + mc) * CHUNK;
    const int col0 = ct * 64;

    f32x4 acc[MI][4];
#pragma unroll
    for (int i = 0; i < MI; i++)
#pragma unroll
        for (int j = 0; j < 4; j++) acc[i][j] = 0.0f;

    const ushort* Aw = A + (size_t)(row0 + wave * MI * 16 + lc) * K + qd * 8;
    const ushort* Bw = Bt + (size_t)(col0 + wave * 16 + (lane >> 2)) * K + (lane & 3) * 8;
    ushort* Bsw = &sm[wave * 512];

    const int NKC = K / 384;
    for (int kc = 0; kc < NKC; ++kc) {
        if (kc) __syncthreads();               // done reading prev B chunk
#pragma unroll
        for (int j = 0; j < 12; j++)
            gll16(Bw + kc * 384 + j * 32, Bsw + j * 2048);
        __syncthreads();                       // drains vmcnt: B chunk landed

        const ushort* Akc = Aw + kc * 384;
#pragma unroll
        for (int kk = 0; kk < 12; ++kk) {
            bf16x8 af[MI];
#pragma unroll
            for (int mi = 0; mi < MI; mi++)
                af[mi] = *(const bf16x8*)(Akc + (size_t)mi * 16 * K + kk * 32);
            bf16x8 bfr[4];
#pragma unroll
            for (int ni = 0; ni < 4; ni++)
                bfr[ni] = *(const bf16x8*)&sm[kk * 2048 + (ni * 16 + lc) * 32 + qd * 8];
            __builtin_amdgcn_s_setprio(1);
#pragma unroll
            for (int mi = 0; mi < MI; mi++)
#pragma unroll
                for (int ni = 0; ni < 4; ni++)
                    acc[mi][ni] = __builtin_amdgcn_mfma_f32_16x16x32_bf16(
                        af[mi], bfr[ni], acc[mi][ni], 0, 0, 0);
            __builtin_amdgcn_s_setprio(0);
        }
    }

    // Epilogue: per-wave region of Cs (overlays Bs), coalesced b128 stores.
    __syncthreads();                           // all waves done with Bs
    ushort* Csw = &sm[wave * MI * 16 * 68];
#pragma unroll
    for (int mi = 0; mi < MI; mi++)
#pragma unroll
        for (int r = 0; r < 4; r++) {
            int lr = mi * 16 + qd * 4 + r;
#pragma unroll
            for (int ni = 0; ni < 4; ni++) {
                float v = acc[mi][ni][r];
                if (bias) v += bias[col0 + ni * 16 + lc];
                if (relu) v = fmaxf(v, 0.0f);
                Csw[lr * 68 + ni * 16 + lc] = f2b(v);
            }
        }
    asm volatile("s_waitcnt lgkmcnt(0)" ::: "memory");  // wave-private region
    const int rowW = row0 + wave * MI * 16;
#pragma unroll
    for (int p = 0; p < MI * 2; p++) {
        int lr = p * 8 + (lane >> 3), cc = (lane & 7) * 8;
        size_t base = (size_t)(rowW + lr) * N + col0 + cc;
        i32x4 d = *(const i32x4*)&Csw[lr * 68 + cc];
        if (resb) d = add_resb(d, __builtin_nontemporal_load((const i32x4*)&resb[base]));
        else if (resf) d = add_resf(d,
                __builtin_nontemporal_load((const f32x4*)&resf[base]),
                __builtin_nontemporal_load((const f32x4*)&resf[base + 4]));
        __builtin_nontemporal_store(d, (i32x4*)&C[base]);
    }
}

// ---------------------------------------------------------------------------
// Fused q2 + kv2 (both K=384), B-stationary MI=2, same structure + NT stores.
// col tiles 0..5 -> C1(N=384), 6..17 -> C2(N=768). Grid 8*16*18 = 2304.
// ---------------------------------------------------------------------------
__global__ __launch_bounds__(256) void gemm_bs_dual(
    const ushort* __restrict__ A1, const ushort* __restrict__ B1t,
    ushort* __restrict__ C1, const float* __restrict__ bias1, int N1,
    const ushort* __restrict__ A2, const ushort* __restrict__ B2t,
    ushort* __restrict__ C2, const float* __restrict__ bias2, int N2,
    int split)
{
    __shared__ __align__(16) ushort sm[24576];
    const int K = 384;
    const int tid  = threadIdx.x;
    const int wave = tid >> 6, lane = tid & 63;
    const int qd = lane >> 4, lc = lane & 15;
    const int id = blockIdx.x, xcd = id & 7, sub = id >> 3;
    const int mc = sub & 15, ct = sub >> 4;
    const int row0 = (xcd * 16 + mc) * 128;
    const bool first = ct < split;
    const ushort* A  = first ? A1 : A2;
    const ushort* Bt = first ? B1t : B2t;
    ushort* C        = first ? C1 : C2;
    const float* bias = first ? bias1 : bias2;
    const int N      = first ? N1 : N2;
    const int col0   = (first ? ct : ct - split) * 64;

    f32x4 acc[2][4];
#pragma unroll
    for (int i = 0; i < 2; i++)
#pragma unroll
        for (int j = 0; j < 4; j++) acc[i][j] = 0.0f;

    const ushort* Aw = A + (size_t)(row0 + wave * 32 + lc) * K + qd * 8;
    const ushort* Bw = Bt + (size_t)(col0 + wave * 16 + (lane >> 2)) * K + (lane & 3) * 8;
    ushort* Bsw = &sm[wave * 512];

#pragma unroll
    for (int j = 0; j < 12; j++)
        gll16(Bw + j * 32, Bsw + j * 2048);
    __syncthreads();

#pragma unroll
    for (int kk = 0; kk < 12; ++kk) {
        bf16x8 af[2];
#pragma unroll
        for (int mi = 0; mi < 2; mi++)
            af[mi] = *(const bf16x8*)(Aw + (size_t)mi * 16 * K + kk * 32);
        bf16x8 bfr[4];
#pragma unroll
        for (int ni = 0; ni < 4; ni++)
            bfr[ni] = *(const bf16x8*)&sm[kk * 2048 + (ni * 16 + lc) * 32 + qd * 8];
        __builtin_amdgcn_s_setprio(1);
#pragma unroll
        for (int mi = 0; mi < 2; mi++)
#pragma unroll
            for (int ni = 0; ni < 4; ni++)
                acc[mi][ni] = __builtin_amdgcn_mfma_f32_16x16x32_bf16(
                    af[mi], bfr[ni], acc[mi][ni], 0, 0, 0);
        __builtin_amdgcn_s_setprio(0);
    }

    __syncthreads();
    ushort* Csw = &sm[wave * 32 * 68];
#pragma unroll
    for (int mi = 0; mi < 2; mi++)
#pragma unroll
        for (int r = 0; r < 4; r++) {
            int lr = mi * 16 + qd * 4 + r;
#pragma unroll
            for (int ni = 0; ni < 4; ni++)
                Csw[lr * 68 + ni * 16 + lc] = f2b(acc[mi][ni][r] + bias[col0 + ni * 16 + lc]);
        }
    asm volatile("s_waitcnt lgkmcnt(0)" ::: "memory");
    const int rowW = row0 + wave * 32;
#pragma unroll
    for (int p = 0; p < 4; p++) {
        int lr = p * 8 + (lane >> 3), cc = (lane & 7) * 8;
        size_t base = (size_t)(rowW + lr) * N + col0 + cc;
        __builtin_nontemporal_store(*(const i32x4*)&Csw[lr * 68 + cc], (i32x4*)&C[base]);
    }
}

// ---------------------------------------------------------------------------
// Attention: one block per (b, h, 64-row q tile). Causal tril + softmax.
// ---------------------------------------------------------------------------
__global__ __launch_bounds__(256) void attn(
    const ushort* __restrict__ q, int qstr,
    const ushort* __restrict__ k, int kstr,
    const ushort* __restrict__ v, int vstr,
    ushort* __restrict__ out)
{
    __shared__ __align__(16) ushort Qs[64 * 72];
    __shared__ __align__(16) ushort Kc[64 * 72];
    __shared__ __align__(16) ushort Vc[64 * 72];
    __shared__ __align__(16) ushort Ps[64 * 264];

    const int tid = threadIdx.x;
    const int wave = tid >> 6, lane = tid & 63;
    const int qd = lane >> 4, lc = lane & 15;
    const int b = blockIdx.z, h = blockIdx.y, t0 = blockIdx.x * 64;
    const int hc = h * 64;
    const float scale = 0.051031036307982884f;  // 384^-0.5 (faithful: E, not HS)

    {
        int r = tid >> 2, c = (tid & 3) * 16;
        int4 q0 = *(const int4*)&q[(size_t)(b * 256 + t0 + r) * qstr + hc + c];
        int4 q1 = *(const int4*)&q[(size_t)(b * 256 + t0 + r) * qstr + hc + c + 8];
        *(int4*)&Qs[r * 72 + c] = q0;
        *(int4*)&Qs[r * 72 + c + 8] = q1;
    }

    f32x4 accS[16];
#pragma unroll
    for (int j = 0; j < 16; j++) accS[j] = 0.0f;

    for (int uc = 0; uc < 4; uc++) {
        int r = tid >> 2, c = (tid & 3) * 16;
        int4 k0v = *(const int4*)&k[(size_t)(b * 256 + uc * 64 + r) * kstr + hc + c];
        int4 k1v = *(const int4*)&k[(size_t)(b * 256 + uc * 64 + r) * kstr + hc + c + 8];
        __syncthreads();
        *(int4*)&Kc[r * 72 + c] = k0v;
        *(int4*)&Kc[r * 72 + c + 8] = k1v;
        __syncthreads();
#pragma unroll
        for (int s0 = 0; s0 < 64; s0 += 32) {
            bf16x8 a = *(const bf16x8*)&Qs[(wave * 16 + lc) * 72 + s0 + qd * 8];
#pragma unroll
            for (int ni = 0; ni < 4; ni++) {
                bf16x8 bb = *(const bf16x8*)&Kc[(ni * 16 + lc) * 72 + s0 + qd * 8];
                accS[uc * 4 + ni] =
                    __builtin_amdgcn_mfma_f32_16x16x32_bf16(a, bb, accS[uc * 4 + ni], 0, 0, 0);
            }
        }
    }

#pragma unroll
    for (int rr = 0; rr < 4; rr++) {
        int t = t0 + wave * 16 + qd * 4 + rr;
        float pv[16];
        float mx = -3.0e38f;
#pragma unroll
        for (int j = 0; j < 16; j++) {
            int u = (j >> 2) * 64 + (j & 3) * 16 + lc;
            float s = accS[j][rr] * scale;
            s = (u <= t) ? s : -3.0e38f;
            pv[j] = s;
            mx = fmaxf(mx, s);
        }
#pragma unroll
        for (int m = 1; m < 16; m <<= 1) mx = fmaxf(mx, __shfl_xor(mx, m, 16));
        float sum = 0.0f;
#pragma unroll
        for (int j = 0; j < 16; j++) { float p = __expf(pv[j] - mx); pv[j] = p; sum += p; }
#pragma unroll
        for (int m = 1; m < 16; m <<= 1) sum += __shfl_xor(sum, m, 16);
        float inv = 1.0f / sum;
#pragma unroll
        for (int j = 0; j < 16; j++) {
            int u = (j >> 2) * 64 + (j & 3) * 16 + lc;
            Ps[(wave * 16 + qd * 4 + rr) * 264 + u] = f2b(pv[j] * inv);
        }
    }

    f32x4 accO[4];
#pragma unroll
    for (int j = 0; j < 4; j++) accO[j] = 0.0f;
    for (int uc = 0; uc < 4; uc++) {
        int r = tid >> 2, s0 = (tid & 3) * 16;
        int4 v0 = *(const int4*)&v[(size_t)(b * 256 + uc * 64 + r) * vstr + hc + s0];
        int4 v1 = *(const int4*)&v[(size_t)(b * 256 + uc * 64 + r) * vstr + hc + s0 + 8];
        __syncthreads();
        {
            const ushort* t0p = (const ushort*)&v0;
            const ushort* t1p = (const ushort*)&v1;
#pragma unroll
            for (int j = 0; j < 8; j++) Vc[(s0 + j) * 72 + r] = t0p[j];
#pragma unroll
            for (int j = 0; j < 8; j++) Vc[(s0 + 8 + j) * 72 + r] = t1p[j];
        }
        __syncthreads();
#pragma unroll
        for (int u0 = 0; u0 < 64; u0 += 32) {
            bf16x8 a = *(const bf16x8*)&Ps[(wave * 16 + lc) * 264 + uc * 64 + u0 + qd * 8];
#pragma unroll
            for (int ni = 0; ni < 4; ni++) {
                bf16x8 bb = *(const bf16x8*)&Vc[(ni * 16 + lc) * 72 + u0 + qd * 8];
                accO[ni] = __builtin_amdgcn_mfma_f32_16x16x32_bf16(a, bb, accO[ni], 0, 0, 0);
            }
        }
    }

#pragma unroll
    for (int ni = 0; ni < 4; ni++)
#pragma unroll
        for (int rr = 0; rr < 4; rr++) {
            int t = t0 + wave * 16 + qd * 4 + rr;
            out[(size_t)(b * 256 + t) * 384 + hc + ni * 16 + lc] = f2b(accO[ni][rr]);
        }
}

// ---------------------------------------------------------------------------
// LayerNorm rows of 384. One wave per row. g/be f32; in bf16; out bf16 or f32.
// ---------------------------------------------------------------------------
__global__ __launch_bounds__(256) void lnorm(
    const ushort* __restrict__ in, const float* __restrict__ g,
    const float* __restrict__ be, ushort* __restrict__ outb,
    float* __restrict__ outf)
{
    const int wave = threadIdx.x >> 6, lane = threadIdx.x & 63;
    const int row = blockIdx.x * 4 + wave;
    const ushort* r = in + (size_t)row * 384;
    float x[6], s1 = 0.0f, s2 = 0.0f;
#pragma unroll
    for (int j = 0; j < 6; j++) {
        x[j] = b2f(r[j * 64 + lane]);
        s1 += x[j]; s2 += x[j] * x[j];
    }
#pragma unroll
    for (int m = 1; m < 64; m <<= 1) {
        s1 += __shfl_xor(s1, m, 64);
        s2 += __shfl_xor(s2, m, 64);
    }
    float mean = s1 * (1.0f / 384.0f);
    float var  = s2 * (1.0f / 384.0f) - mean * mean;
    float rstd = rsqrtf(var + 1e-5f);
#pragma unroll
    for (int j = 0; j < 6; j++) {
        float y = (x[j] - mean) * rstd * g[j * 64 + lane] + be[j * 64 + lane];
        if (outb) outb[(size_t)row * 384 + j * 64 + lane] = f2b(y);
        if (outf) outf[(size_t)row * 384 + j * 64 + lane] = y;
    }
}

// ---------------------------------------------------------------------------
// Fused prep (unchanged).
// ---------------------------------------------------------------------------
__device__ __forceinline__ void dev_cvt(const float* in, ushort* out, int blk) {
    size_t i = ((size_t)blk * 256 + threadIdx.x) * 8;
    float4 a = *(const float4*)(in + i);
    float4 b = *(const float4*)(in + i + 4);
    *(int4*)(out + i) = pack8(a, b);
}
__device__ __forceinline__ void dev_transp(const float* in, ushort* out,
                                           int R, int C, int bx, int by,
                                           float (*t)[33]) {
    const int tx = threadIdx.x & 31, ty = threadIdx.x >> 5;
    const int c0 = bx * 32, r0 = by * 32;
#pragma unroll
    for (int i = 0; i < 32; i += 8)
        t[ty + i][tx] = in[(size_t)(r0 + ty + i) * C + c0 + tx];
    __syncthreads();
#pragma unroll
    for (int i = 0; i < 32; i += 8)
        out[(size_t)(c0 + ty + i) * R + r0 + tx] = f2b(t[tx][ty + i]);
}
__device__ __forceinline__ void dev_packqkv(const float* wq, const float* wk,
                                            const float* wv, ushort* Wt,
                                            int blk, float (*t)[33]) {
    const int tx = threadIdx.x & 31, ty = threadIdx.x >> 5;
    const int bx = blk % 12, by = (blk / 12) % 2, bz = blk / 24;
    const int e0 = bx * 32, s0 = by * 32;
    const int seg = bz / 6, h = bz - seg * 6;
    const float* w = (seg == 0) ? wq : (seg == 1) ? wk : wv;
    const float* wh = w + (size_t)h * 384 * 64;
#pragma unroll
    for (int i = 0; i < 32; i += 8)
        t[ty + i][tx] = wh[(size_t)(e0 + ty + i) * 64 + s0 + tx];
    __syncthreads();
    const int nbase = seg * 384 + h * 64 + s0;
#pragma unroll
    for (int i = 0; i < 32; i += 8)
        Wt[(size_t)(nbase + ty + i) * 384 + e0 + tx] = f2b(t[tx][ty + i]);
}

__global__ __launch_bounds__(256) void prep_all(
    const float* __restrict__ x, ushort* __restrict__ xb,
    const float* __restrict__ enc, ushort* __restrict__ encb,
    const float* __restrict__ s1wq, const float* __restrict__ s1wk,
    const float* __restrict__ s1wv, ushort* __restrict__ W1,
    const float* __restrict__ s2wq, const float* __restrict__ s2wk,
    const float* __restrict__ s2wv, ushort* __restrict__ W2,
    const float* __restrict__ s1pw, ushort* __restrict__ pw1t,
    const float* __restrict__ s2pw, ushort* __restrict__ pw2t,
    const float* __restrict__ fw1, ushort* __restrict__ w1t,
    const float* __restrict__ fw2, ushort* __restrict__ w2t,
    const float* __restrict__ s1bq, const float* __restrict__ s1bk,
    const float* __restrict__ s1bv, const float* __restrict__ s2bq,
    const float* __restrict__ s2bk, const float* __restrict__ s2bv,
    float* __restrict__ bias1, float* __restrict__ bias2)
{
    __shared__ float t[32][33];
    int blk = blockIdx.x;
    if (blk < 3072) { dev_cvt(x, xb, blk); return; }
    blk -= 3072;
    if (blk < 3072) { dev_cvt(enc, encb, blk); return; }
    blk -= 3072;
    if (blk < 432) { dev_packqkv(s1wq, s1wk, s1wv, W1, blk, t); return; }
    blk -= 432;
    if (blk < 432) { dev_packqkv(s2wq, s2wk, s2wv, W2, blk, t); return; }
    blk -= 432;
    if (blk < 144) { dev_transp(s1pw, pw1t, 384, 384, blk % 12, blk / 12, t); return; }
    blk -= 144;
    if (blk < 144) { dev_transp(s2pw, pw2t, 384, 384, blk % 12, blk / 12, t); return; }
    blk -= 144;
    if (blk < 576) { dev_transp(fw1, w1t, 384, 1536, blk % 48, blk / 48, t); return; }
    blk -= 576;
    if (blk < 576) { dev_transp(fw2, w2t, 1536, 384, blk % 12, blk / 12, t); return; }
    blk -= 576;
    int i = blk * 256 + threadIdx.x;
    if (i >= 2304) return;
    int grp = i / 1152, r = i - grp * 1152;
    int seg = r / 384, nn = r - seg * 384;
    const float* src = grp == 0 ? (seg == 0 ? s1bq : seg == 1 ? s1bk : s1bv)
                                : (seg == 0 ? s2bq : seg == 1 ? s2bk : s2bv);
    (grp == 0 ? bias1 : bias2)[r] = src[nn];
}

// ---------------------------------------------------------------------------
extern "C" void kernel_launch(void* const* d_in, const int* in_sizes, int n_in,
                              void* d_out, int out_size, void* d_ws, size_t ws_size,
                              hipStream_t stream)
{
    const float* enc = (const float*)d_in[0];
    const float* x   = (const float*)d_in[1];
    const float* s1wq = (const float*)d_in[2];  const float* s1bq = (const float*)d_in[3];
    const float* s1wk = (const float*)d_in[4];  const float* s1bk = (const float*)d_in[5];
    const float* s1wv = (const float*)d_in[6];  const float* s1bv = (const float*)d_in[7];
    const float* s1pw = (const float*)d_in[8];  const float* s1pb = (const float*)d_in[9];
    const float* s2wq = (const float*)d_in[10]; const float* s2bq = (const float*)d_in[11];
    const float* s2wk = (const float*)d_in[12]; const float* s2bk = (const float*)d_in[13];
    const float* s2wv = (const float*)d_in[14]; const float* s2bv = (const float*)d_in[15];
    const float* s2pw = (const float*)d_in[16]; const float* s2pb = (const float*)d_in[17];
    const float* fw1 = (const float*)d_in[18];  const float* fb1 = (const float*)d_in[19];
    const float* fw2 = (const float*)d_in[20];  const float* fb2 = (const float*)d_in[21];
    const float* g1 = (const float*)d_in[22];   const float* be1 = (const float*)d_in[23];
    const float* g2 = (const float*)d_in[24];   const float* be2 = (const float*)d_in[25];
    const float* g3 = (const float*)d_in[26];   const float* be3 = (const float*)d_in[27];

    if (ws_size < 80216064u) return;  // proven-available scratch size

    ushort* wsp = (ushort*)d_ws;           // ushort-element offsets
    ushort* qkv1 = wsp;
    ushort* q2   = wsp;
    ushort* kv2  = wsp + 6291456;
    ushort* h1   = wsp;
    ushort* att  = wsp + 18874368;         // [16384,384]; xb shares (dead before attn1)
    ushort* xb   = wsp + 18874368;
    ushort* tmp  = wsp + 25165824;         // [16384,384] pre-LN
    ushort* o1b  = wsp + 31457280;         // [16384,384]
    ushort* W1   = wsp + 37748736;         // [1152,384]
    ushort* W2   = W1 + 442368;
    ushort* pw1t = W2 + 442368;            // [384,384]
    ushort* pw2t = pw1t + 147456;          // [384,384]
    ushort* w1t  = pw2t + 147456;          // [1536,384]
    ushort* w2t  = w1t + 589824;           // [384,1536]

    ushort* encb = (ushort*)d_out;         // dead after kv2 gemm
    ushort* o2b  = (ushort*)d_out;
    float* bias1 = (float*)((ushort*)d_out + 6291456);
    float* bias2 = bias1 + 1152;

    // fused prep (1 dispatch)
    prep_all<<<dim3(8457), dim3(256), 0, stream>>>(
        x, xb, enc, encb,
        s1wq, s1wk, s1wv, W1, s2wq, s2wk, s2wv, W2,
        s1pw, pw1t, s2pw, pw2t, fw1, w1t, fw2, w2t,
        s1bq, s1bk, s1bv, s2bq, s2bk, s2bv, bias1, bias2);

    // stage 1: qkv (MI=4: grid 8*8*18), attn, proj (MI=2: grid 8*16*6), ln
    gemm_bs<4><<<dim3(1152), dim3(256), 0, stream>>>(
        xb, W1, qkv1, bias1, nullptr, nullptr, 1152, 384, 0);
    attn<<<dim3(4, 6, 64), dim3(256), 0, stream>>>(
        qkv1, 1152, qkv1 + 384, 1152, qkv1 + 768, 1152, att);
    gemm_bs<2><<<dim3(768), dim3(256), 0, stream>>>(
        att, pw1t, tmp, s1pb, nullptr, x, 384, 384, 0);
    lnorm<<<dim3(4096), dim3(256), 0, stream>>>(tmp, g1, be1, o1b, nullptr);

    // stage 2 (q2 + kv2 fused: grid 8*16*18)
    gemm_bs_dual<<<dim3(2304), dim3(256), 0, stream>>>(
        o1b, W2, q2, bias2, 384,
        encb, W2 + 147456, kv2, bias2 + 384, 768, 6);
    attn<<<dim3(4, 6, 64), dim3(256), 0, stream>>>(
        q2, 384, kv2, 768, kv2 + 384, 768, att);
    gemm_bs<2><<<dim3(768), dim3(256), 0, stream>>>(
        att, pw2t, tmp, s2pb, o1b, nullptr, 384, 384, 0);
    lnorm<<<dim3(4096), dim3(256), 0, stream>>>(tmp, g2, be2, o2b, nullptr);

    // stage 3: ffn1 (MI=4: grid 8*8*24), ffn2 (MI=2, K=1536: grid 8*16*6)
    gemm_bs<4><<<dim3(1536), dim3(256), 0, stream>>>(
        o2b, w1t, h1, fb1, nullptr, nullptr, 1536, 384, 1);
    gemm_bs<2><<<dim3(768), dim3(256), 0, stream>>>(
        h1, w2t, tmp, fb2, o2b, nullptr, 384, 1536, 0);
    lnorm<<<dim3(4096), dim3(256), 0, stream>>>(tmp, g3, be3, nullptr, (float*)d_out);
}

// Round 9
// 464.192 us; speedup vs baseline: 1.0813x; 1.0405x over previous
//
#include <hip/hip_runtime.h>

// Internal pipeline bf16 (ushort bits); external inputs/outputs float32.
typedef __attribute__((ext_vector_type(8))) short bf16x8;
typedef __attribute__((ext_vector_type(4))) float f32x4;
typedef __attribute__((ext_vector_type(4))) int i32x4;

__device__ __forceinline__ float b2f(ushort b) {
    union { unsigned int u; float f; } x;
    x.u = ((unsigned int)b) << 16;
    return x.f;
}
__device__ __forceinline__ ushort f2b(float f) {
    union { float f; unsigned int u; } x;
    x.f = f;
    unsigned int r = x.u + 0x7fffu + ((x.u >> 16) & 1u);
    return (ushort)(r >> 16);
}
__device__ __forceinline__ int4 pack8(float4 a, float4 b) {
    union { int4 v; ushort u[8]; } r;
    r.u[0] = f2b(a.x); r.u[1] = f2b(a.y); r.u[2] = f2b(a.z); r.u[3] = f2b(a.w);
    r.u[4] = f2b(b.x); r.u[5] = f2b(b.y); r.u[6] = f2b(b.z); r.u[7] = f2b(b.w);
    return r.v;
}
// cs + resb (both bf16x8 as i32x4) -> bf16x8
__device__ __forceinline__ i32x4 add_resb(i32x4 cs, i32x4 rs) {
    const ushort* c = (const ushort*)&cs; const ushort* r = (const ushort*)&rs;
    union { i32x4 v; ushort u[8]; } o;
#pragma unroll
    for (int j = 0; j < 8; j++) o.u[j] = f2b(b2f(c[j]) + b2f(r[j]));
    return o.v;
}
__device__ __forceinline__ i32x4 add_resf(i32x4 cs, f32x4 r0, f32x4 r1) {
    const ushort* c = (const ushort*)&cs;
    union { i32x4 v; ushort u[8]; } o;
#pragma unroll
    for (int j = 0; j < 4; j++) o.u[j] = f2b(b2f(c[j]) + r0[j]);
#pragma unroll
    for (int j = 0; j < 4; j++) o.u[4 + j] = f2b(b2f(c[4 + j]) + r1[j]);
    return o.v;
}

// Async global->LDS, 16B per lane (wave writes lds_base + lane*16).
__device__ __forceinline__ void gll16(const ushort* g, ushort* l) {
    __builtin_amdgcn_global_load_lds(
        (__attribute__((address_space(1))) void*)(g),
        (__attribute__((address_space(3))) void*)(l), 16, 0, 0);
}

// ---------------------------------------------------------------------------
// B-stationary GEMM, occupancy-first (R9). Block = 64 cols x 128 rows
// (4 waves x 32 rows). B staged in K=128 sub-chunks (16KB, single-buffered,
// R4 subtile layout) instead of the full 48KB K-panel: total LDS 17.4KB ->
// 7 blocks/CU co-resident (vs 3), so the latency-serialized per-wave load
// chains of 7 blocks overlap. Hot loop / A-pattern / NT epilogue = R8 (best).
// ---------------------------------------------------------------------------
template<int MI>   // MI=2 only
__global__ __launch_bounds__(256) void gemm_bs(
    const ushort* __restrict__ A, const ushort* __restrict__ Bt,
    ushort* __restrict__ C, const float* __restrict__ bias,
    const ushort* __restrict__ resb, const float* __restrict__ resf,
    int N, int K, int relu)
{
    __shared__ __align__(16) ushort sm[8704];      // staging 8192 + Cs overlay
    constexpr int CHUNK = MI * 64;                 // 128 rows per block
    constexpr int PERX  = (16384 / CHUNK) / 8;     // 16 row-chunks per XCD
    const int tid  = threadIdx.x;
    const int wave = tid >> 6, lane = tid & 63;
    const int qd = lane >> 4, lc = lane & 15;
    const int id = blockIdx.x, xcd = id & 7, sub = id >> 3;
    const int mc = sub % PERX, ct = sub / PERX;
    const int row0 = (xcd * PERX + mc) * CHUNK;
    const int col0 = ct * 64;

    f32x4 acc[MI][4];
#pragma unroll
    for (int i = 0; i < MI; i++)
#pragma unroll
        for (int j = 0; j < 4; j++) acc[i][j] = 0.0f;

    const ushort* Aw = A + (size_t)(row0 + wave * MI * 16 + lc) * K + qd * 8;
    const ushort* Bw = Bt + (size_t)(col0 + wave * 16 + (lane >> 2)) * K + (lane & 3) * 8;
    ushort* Bsw = &sm[wave * 512];

    const int NKC = K >> 7;                        // K/128 chunks
    for (int kc = 0; kc < NKC; ++kc) {
        if (kc) __syncthreads();                   // done reading prev chunk
#pragma unroll
        for (int j = 0; j < 4; j++)                // 4 subtiles = 16KB
            gll16(Bw + kc * 128 + j * 32, Bsw + j * 2048);
        __syncthreads();                           // drains vmcnt: chunk landed

        const ushort* Akc = Aw + kc * 128;
#pragma unroll
        for (int kk = 0; kk < 4; ++kk) {
            bf16x8 af[MI];
#pragma unroll
            for (int mi = 0; mi < MI; mi++)
                af[mi] = *(const bf16x8*)(Akc + (size_t)mi * 16 * K + kk * 32);
            bf16x8 bfr[4];
#pragma unroll
            for (int ni = 0; ni < 4; ni++)
                bfr[ni] = *(const bf16x8*)&sm[kk * 2048 + (ni * 16 + lc) * 32 + qd * 8];
            __builtin_amdgcn_s_setprio(1);
#pragma unroll
            for (int mi = 0; mi < MI; mi++)
#pragma unroll
                for (int ni = 0; ni < 4; ni++)
                    acc[mi][ni] = __builtin_amdgcn_mfma_f32_16x16x32_bf16(
                        af[mi], bfr[ni], acc[mi][ni], 0, 0, 0);
            __builtin_amdgcn_s_setprio(0);
        }
    }

    // Epilogue: per-wave region of Cs (overlays staging), coalesced stores.
    __syncthreads();                               // all waves done with sm
    ushort* Csw = &sm[wave * MI * 16 * 68];
#pragma unroll
    for (int mi = 0; mi < MI; mi++)
#pragma unroll
        for (int r = 0; r < 4; r++) {
            int lr = mi * 16 + qd * 4 + r;
#pragma unroll
            for (int ni = 0; ni < 4; ni++) {
                float v = acc[mi][ni][r];
                if (bias) v += bias[col0 + ni * 16 + lc];
                if (relu) v = fmaxf(v, 0.0f);
                Csw[lr * 68 + ni * 16 + lc] = f2b(v);
            }
        }
    asm volatile("s_waitcnt lgkmcnt(0)" ::: "memory");  // wave-private region
    const int rowW = row0 + wave * MI * 16;
#pragma unroll
    for (int p = 0; p < MI * 2; p++) {
        int lr = p * 8 + (lane >> 3), cc = (lane & 7) * 8;
        size_t base = (size_t)(rowW + lr) * N + col0 + cc;
        i32x4 d = *(const i32x4*)&Csw[lr * 68 + cc];
        if (resb) d = add_resb(d, __builtin_nontemporal_load((const i32x4*)&resb[base]));
        else if (resf) d = add_resf(d,
                __builtin_nontemporal_load((const f32x4*)&resf[base]),
                __builtin_nontemporal_load((const f32x4*)&resf[base + 4]));
        __builtin_nontemporal_store(d, (i32x4*)&C[base]);
    }
}

// ---------------------------------------------------------------------------
// Fused q2 + kv2 (both K=384), same chunked structure, MI=2.
// col tiles 0..5 -> C1(N=384), 6..17 -> C2(N=768). Grid 8*16*18 = 2304.
// ---------------------------------------------------------------------------
__global__ __launch_bounds__(256) void gemm_bs_dual(
    const ushort* __restrict__ A1, const ushort* __restrict__ B1t,
    ushort* __restrict__ C1, const float* __restrict__ bias1, int N1,
    const ushort* __restrict__ A2, const ushort* __restrict__ B2t,
    ushort* __restrict__ C2, const float* __restrict__ bias2, int N2,
    int split)
{
    __shared__ __align__(16) ushort sm[8704];
    const int K = 384;
    const int tid  = threadIdx.x;
    const int wave = tid >> 6, lane = tid & 63;
    const int qd = lane >> 4, lc = lane & 15;
    const int id = blockIdx.x, xcd = id & 7, sub = id >> 3;
    const int mc = sub & 15, ct = sub >> 4;
    const int row0 = (xcd * 16 + mc) * 128;
    const bool first = ct < split;
    const ushort* A  = first ? A1 : A2;
    const ushort* Bt = first ? B1t : B2t;
    ushort* C        = first ? C1 : C2;
    const float* bias = first ? bias1 : bias2;
    const int N      = first ? N1 : N2;
    const int col0   = (first ? ct : ct - split) * 64;

    f32x4 acc[2][4];
#pragma unroll
    for (int i = 0; i < 2; i++)
#pragma unroll
        for (int j = 0; j < 4; j++) acc[i][j] = 0.0f;

    const ushort* Aw = A + (size_t)(row0 + wave * 32 + lc) * K + qd * 8;
    const ushort* Bw = Bt + (size_t)(col0 + wave * 16 + (lane >> 2)) * K + (lane & 3) * 8;
    ushort* Bsw = &sm[wave * 512];

    for (int kc = 0; kc < 3; ++kc) {
        if (kc) __syncthreads();
#pragma unroll
        for (int j = 0; j < 4; j++)
            gll16(Bw + kc * 128 + j * 32, Bsw + j * 2048);
        __syncthreads();

        const ushort* Akc = Aw + kc * 128;
#pragma unroll
        for (int kk = 0; kk < 4; ++kk) {
            bf16x8 af[2];
#pragma unroll
            for (int mi = 0; mi < 2; mi++)
                af[mi] = *(const bf16x8*)(Akc + (size_t)mi * 16 * K + kk * 32);
            bf16x8 bfr[4];
#pragma unroll
            for (int ni = 0; ni < 4; ni++)
                bfr[ni] = *(const bf16x8*)&sm[kk * 2048 + (ni * 16 + lc) * 32 + qd * 8];
            __builtin_amdgcn_s_setprio(1);
#pragma unroll
            for (int mi = 0; mi < 2; mi++)
#pragma unroll
                for (int ni = 0; ni < 4; ni++)
                    acc[mi][ni] = __builtin_amdgcn_mfma_f32_16x16x32_bf16(
                        af[mi], bfr[ni], acc[mi][ni], 0, 0, 0);
            __builtin_amdgcn_s_setprio(0);
        }
    }

    __syncthreads();
    ushort* Csw = &sm[wave * 32 * 68];
#pragma unroll
    for (int mi = 0; mi < 2; mi++)
#pragma unroll
        for (int r = 0; r < 4; r++) {
            int lr = mi * 16 + qd * 4 + r;
#pragma unroll
            for (int ni = 0; ni < 4; ni++)
                Csw[lr * 68 + ni * 16 + lc] = f2b(acc[mi][ni][r] + bias[col0 + ni * 16 + lc]);
        }
    asm volatile("s_waitcnt lgkmcnt(0)" ::: "memory");
    const int rowW = row0 + wave * 32;
#pragma unroll
    for (int p = 0; p < 4; p++) {
        int lr = p * 8 + (lane >> 3), cc = (lane & 7) * 8;
        size_t base = (size_t)(rowW + lr) * N + col0 + cc;
        __builtin_nontemporal_store(*(const i32x4*)&Csw[lr * 68 + cc], (i32x4*)&C[base]);
    }
}

// ---------------------------------------------------------------------------
// Attention: one block per (b, h, 64-row q tile). Causal tril + softmax.
// ---------------------------------------------------------------------------
__global__ __launch_bounds__(256) void attn(
    const ushort* __restrict__ q, int qstr,
    const ushort* __restrict__ k, int kstr,
    const ushort* __restrict__ v, int vstr,
    ushort* __restrict__ out)
{
    __shared__ __align__(16) ushort Qs[64 * 72];
    __shared__ __align__(16) ushort Kc[64 * 72];
    __shared__ __align__(16) ushort Vc[64 * 72];
    __shared__ __align__(16) ushort Ps[64 * 264];

    const int tid = threadIdx.x;
    const int wave = tid >> 6, lane = tid & 63;
    const int qd = lane >> 4, lc = lane & 15;
    const int b = blockIdx.z, h = blockIdx.y, t0 = blockIdx.x * 64;
    const int hc = h * 64;
    const float scale = 0.051031036307982884f;  // 384^-0.5 (faithful: E, not HS)

    {
        int r = tid >> 2, c = (tid & 3) * 16;
        int4 q0 = *(const int4*)&q[(size_t)(b * 256 + t0 + r) * qstr + hc + c];
        int4 q1 = *(const int4*)&q[(size_t)(b * 256 + t0 + r) * qstr + hc + c + 8];
        *(int4*)&Qs[r * 72 + c] = q0;
        *(int4*)&Qs[r * 72 + c + 8] = q1;
    }

    f32x4 accS[16];
#pragma unroll
    for (int j = 0; j < 16; j++) accS[j] = 0.0f;

    for (int uc = 0; uc < 4; uc++) {
        int r = tid >> 2, c = (tid & 3) * 16;
        int4 k0v = *(const int4*)&k[(size_t)(b * 256 + uc * 64 + r) * kstr + hc + c];
        int4 k1v = *(const int4*)&k[(size_t)(b * 256 + uc * 64 + r) * kstr + hc + c + 8];
        __syncthreads();
        *(int4*)&Kc[r * 72 + c] = k0v;
        *(int4*)&Kc[r * 72 + c + 8] = k1v;
        __syncthreads();
#pragma unroll
        for (int s0 = 0; s0 < 64; s0 += 32) {
            bf16x8 a = *(const bf16x8*)&Qs[(wave * 16 + lc) * 72 + s0 + qd * 8];
#pragma unroll
            for (int ni = 0; ni < 4; ni++) {
                bf16x8 bb = *(const bf16x8*)&Kc[(ni * 16 + lc) * 72 + s0 + qd * 8];
                accS[uc * 4 + ni] =
                    __builtin_amdgcn_mfma_f32_16x16x32_bf16(a, bb, accS[uc * 4 + ni], 0, 0, 0);
            }
        }
    }

#pragma unroll
    for (int rr = 0; rr < 4; rr++) {
        int t = t0 + wave * 16 + qd * 4 + rr;
        float pv[16];
        float mx = -3.0e38f;
#pragma unroll
        for (int j = 0; j < 16; j++) {
            int u = (j >> 2) * 64 + (j & 3) * 16 + lc;
            float s = accS[j][rr] * scale;
            s = (u <= t) ? s : -3.0e38f;
            pv[j] = s;
            mx = fmaxf(mx, s);
        }
#pragma unroll
        for (int m = 1; m < 16; m <<= 1) mx = fmaxf(mx, __shfl_xor(mx, m, 16));
        float sum = 0.0f;
#pragma unroll
        for (int j = 0; j < 16; j++) { float p = __expf(pv[j] - mx); pv[j] = p; sum += p; }
#pragma unroll
        for (int m = 1; m < 16; m <<= 1) sum += __shfl_xor(sum, m, 16);
        float inv = 1.0f / sum;
#pragma unroll
        for (int j = 0; j < 16; j++) {
            int u = (j >> 2) * 64 + (j & 3) * 16 + lc;
            Ps[(wave * 16 + qd * 4 + rr) * 264 + u] = f2b(pv[j] * inv);
        }
    }

    f32x4 accO[4];
#pragma unroll
    for (int j = 0; j < 4; j++) accO[j] = 0.0f;
    for (int uc = 0; uc < 4; uc++) {
        int r = tid >> 2, s0 = (tid & 3) * 16;
        int4 v0 = *(const int4*)&v[(size_t)(b * 256 + uc * 64 + r) * vstr + hc + s0];
        int4 v1 = *(const int4*)&v[(size_t)(b * 256 + uc * 64 + r) * vstr + hc + s0 + 8];
        __syncthreads();
        {
            const ushort* t0p = (const ushort*)&v0;
            const ushort* t1p = (const ushort*)&v1;
#pragma unroll
            for (int j = 0; j < 8; j++) Vc[(s0 + j) * 72 + r] = t0p[j];
#pragma unroll
            for (int j = 0; j < 8; j++) Vc[(s0 + 8 + j) * 72 + r] = t1p[j];
        }
        __syncthreads();
#pragma unroll
        for (int u0 = 0; u0 < 64; u0 += 32) {
            bf16x8 a = *(const bf16x8*)&Ps[(wave * 16 + lc) * 264 + uc * 64 + u0 + qd * 8];
#pragma unroll
            for (int ni = 0; ni < 4; ni++) {
                bf16x8 bb = *(const bf16x8*)&Vc[(ni * 16 + lc) * 72 + u0 + qd * 8];
                accO[ni] = __builtin_amdgcn_mfma_f32_16x16x32_bf16(a, bb, accO[ni], 0, 0, 0);
            }
        }
    }

#pragma unroll
    for (int ni = 0; ni < 4; ni++)
#pragma unroll
        for (int rr = 0; rr < 4; rr++) {
            int t = t0 + wave * 16 + qd * 4 + rr;
            out[(size_t)(b * 256 + t) * 384 + hc + ni * 16 + lc] = f2b(accO[ni][rr]);
        }
}

// ---------------------------------------------------------------------------
// LayerNorm rows of 384. One wave per row. g/be f32; in bf16; out bf16 or f32.
// ---------------------------------------------------------------------------
__global__ __launch_bounds__(256) void lnorm(
    const ushort* __restrict__ in, const float* __restrict__ g,
    const float* __restrict__ be, ushort* __restrict__ outb,
    float* __restrict__ outf)
{
    const int wave = threadIdx.x >> 6, lane = threadIdx.x & 63;
    const int row = blockIdx.x * 4 + wave;
    const ushort* r = in + (size_t)row * 384;
    float x[6], s1 = 0.0f, s2 = 0.0f;
#pragma unroll
    for (int j = 0; j < 6; j++) {
        x[j] = b2f(r[j * 64 + lane]);
        s1 += x[j]; s2 += x[j] * x[j];
    }
#pragma unroll
    for (int m = 1; m < 64; m <<= 1) {
        s1 += __shfl_xor(s1, m, 64);
        s2 += __shfl_xor(s2, m, 64);
    }
    float mean = s1 * (1.0f / 384.0f);
    float var  = s2 * (1.0f / 384.0f) - mean * mean;
    float rstd = rsqrtf(var + 1e-5f);
#pragma unroll
    for (int j = 0; j < 6; j++) {
        float y = (x[j] - mean) * rstd * g[j * 64 + lane] + be[j * 64 + lane];
        if (outb) outb[(size_t)row * 384 + j * 64 + lane] = f2b(y);
        if (outf) outf[(size_t)row * 384 + j * 64 + lane] = y;
    }
}

// ---------------------------------------------------------------------------
// Fused prep (unchanged).
// ---------------------------------------------------------------------------
__device__ __forceinline__ void dev_cvt(const float* in, ushort* out, int blk) {
    size_t i = ((size_t)blk * 256 + threadIdx.x) * 8;
    float4 a = *(const float4*)(in + i);
    float4 b = *(const float4*)(in + i + 4);
    *(int4*)(out + i) = pack8(a, b);
}
__device__ __forceinline__ void dev_transp(const float* in, ushort* out,
                                           int R, int C, int bx, int by,
                                           float (*t)[33]) {
    const int tx = threadIdx.x & 31, ty = threadIdx.x >> 5;
    const int c0 = bx * 32, r0 = by * 32;
#pragma unroll
    for (int i = 0; i < 32; i += 8)
        t[ty + i][tx] = in[(size_t)(r0 + ty + i) * C + c0 + tx];
    __syncthreads();
#pragma unroll
    for (int i = 0; i < 32; i += 8)
        out[(size_t)(c0 + ty + i) * R + r0 + tx] = f2b(t[tx][ty + i]);
}
__device__ __forceinline__ void dev_packqkv(const float* wq, const float* wk,
                                            const float* wv, ushort* Wt,
                                            int blk, float (*t)[33]) {
    const int tx = threadIdx.x & 31, ty = threadIdx.x >> 5;
    const int bx = blk % 12, by = (blk / 12) % 2, bz = blk / 24;
    const int e0 = bx * 32, s0 = by * 32;
    const int seg = bz / 6, h = bz - seg * 6;
    const float* w = (seg == 0) ? wq : (seg == 1) ? wk : wv;
    const float* wh = w + (size_t)h * 384 * 64;
#pragma unroll
    for (int i = 0; i < 32; i += 8)
        t[ty + i][tx] = wh[(size_t)(e0 + ty + i) * 64 + s0 + tx];
    __syncthreads();
    const int nbase = seg * 384 + h * 64 + s0;
#pragma unroll
    for (int i = 0; i < 32; i += 8)
        Wt[(size_t)(nbase + ty + i) * 384 + e0 + tx] = f2b(t[tx][ty + i]);
}

__global__ __launch_bounds__(256) void prep_all(
    const float* __restrict__ x, ushort* __restrict__ xb,
    const float* __restrict__ enc, ushort* __restrict__ encb,
    const float* __restrict__ s1wq, const float* __restrict__ s1wk,
    const float* __restrict__ s1wv, ushort* __restrict__ W1,
    const float* __restrict__ s2wq, const float* __restrict__ s2wk,
    const float* __restrict__ s2wv, ushort* __restrict__ W2,
    const float* __restrict__ s1pw, ushort* __restrict__ pw1t,
    const float* __restrict__ s2pw, ushort* __restrict__ pw2t,
    const float* __restrict__ fw1, ushort* __restrict__ w1t,
    const float* __restrict__ fw2, ushort* __restrict__ w2t,
    const float* __restrict__ s1bq, const float* __restrict__ s1bk,
    const float* __restrict__ s1bv, const float* __restrict__ s2bq,
    const float* __restrict__ s2bk, const float* __restrict__ s2bv,
    float* __restrict__ bias1, float* __restrict__ bias2)
{
    __shared__ float t[32][33];
    int blk = blockIdx.x;
    if (blk < 3072) { dev_cvt(x, xb, blk); return; }
    blk -= 3072;
    if (blk < 3072) { dev_cvt(enc, encb, blk); return; }
    blk -= 3072;
    if (blk < 432) { dev_packqkv(s1wq, s1wk, s1wv, W1, blk, t); return; }
    blk -= 432;
    if (blk < 432) { dev_packqkv(s2wq, s2wk, s2wv, W2, blk, t); return; }
    blk -= 432;
    if (blk < 144) { dev_transp(s1pw, pw1t, 384, 384, blk % 12, blk / 12, t); return; }
    blk -= 144;
    if (blk < 144) { dev_transp(s2pw, pw2t, 384, 384, blk % 12, blk / 12, t); return; }
    blk -= 144;
    if (blk < 576) { dev_transp(fw1, w1t, 384, 1536, blk % 48, blk / 48, t); return; }
    blk -= 576;
    if (blk < 576) { dev_transp(fw2, w2t, 1536, 384, blk % 12, blk / 12, t); return; }
    blk -= 576;
    int i = blk * 256 + threadIdx.x;
    if (i >= 2304) return;
    int grp = i / 1152, r = i - grp * 1152;
    int seg = r / 384, nn = r - seg * 384;
    const float* src = grp == 0 ? (seg == 0 ? s1bq : seg == 1 ? s1bk : s1bv)
                                : (seg == 0 ? s2bq : seg == 1 ? s2bk : s2bv);
    (grp == 0 ? bias1 : bias2)[r] = src[nn];
}

// ---------------------------------------------------------------------------
extern "C" void kernel_launch(void* const* d_in, const int* in_sizes, int n_in,
                              void* d_out, int out_size, void* d_ws, size_t ws_size,
                              hipStream_t stream)
{
    const float* enc = (const float*)d_in[0];
    const float* x   = (const float*)d_in[1];
    const float* s1wq = (const float*)d_in[2];  const float* s1bq = (const float*)d_in[3];
    const float* s1wk = (const float*)d_in[4];  const float* s1bk = (const float*)d_in[5];
    const float* s1wv = (const float*)d_in[6];  const float* s1bv = (const float*)d_in[7];
    const float* s1pw = (const float*)d_in[8];  const float* s1pb = (const float*)d_in[9];
    const float* s2wq = (const float*)d_in[10]; const float* s2bq = (const float*)d_in[11];
    const float* s2wk = (const float*)d_in[12]; const float* s2bk = (const float*)d_in[13];
    const float* s2wv = (const float*)d_in[14]; const float* s2bv = (const float*)d_in[15];
    const float* s2pw = (const float*)d_in[16]; const float* s2pb = (const float*)d_in[17];
    const float* fw1 = (const float*)d_in[18];  const float* fb1 = (const float*)d_in[19];
    const float* fw2 = (const float*)d_in[20];  const float* fb2 = (const float*)d_in[21];
    const float* g1 = (const float*)d_in[22];   const float* be1 = (const float*)d_in[23];
    const float* g2 = (const float*)d_in[24];   const float* be2 = (const float*)d_in[25];
    const float* g3 = (const float*)d_in[26];   const float* be3 = (const float*)d_in[27];

    if (ws_size < 80216064u) return;  // proven-available scratch size

    ushort* wsp = (ushort*)d_ws;           // ushort-element offsets
    ushort* qkv1 = wsp;
    ushort* q2   = wsp;
    ushort* kv2  = wsp + 6291456;
    ushort* h1   = wsp;
    ushort* att  = wsp + 18874368;         // [16384,384]; xb shares (dead before attn1)
    ushort* xb   = wsp + 18874368;
    ushort* tmp  = wsp + 25165824;         // [16384,384] pre-LN
    ushort* o1b  = wsp + 31457280;         // [16384,384]
    ushort* W1   = wsp + 37748736;         // [1152,384]
    ushort* W2   = W1 + 442368;
    ushort* pw1t = W2 + 442368;            // [384,384]
    ushort* pw2t = pw1t + 147456;          // [384,384]
    ushort* w1t  = pw2t + 147456;          // [1536,384]
    ushort* w2t  = w1t + 589824;           // [384,1536]

    ushort* encb = (ushort*)d_out;         // dead after kv2 gemm
    ushort* o2b  = (ushort*)d_out;
    float* bias1 = (float*)((ushort*)d_out + 6291456);
    float* bias2 = bias1 + 1152;

    // fused prep (1 dispatch)
    prep_all<<<dim3(8457), dim3(256), 0, stream>>>(
        x, xb, enc, encb,
        s1wq, s1wk, s1wv, W1, s2wq, s2wk, s2wv, W2,
        s1pw, pw1t, s2pw, pw2t, fw1, w1t, fw2, w2t,
        s1bq, s1bk, s1bv, s2bq, s2bk, s2bv, bias1, bias2);

    // stage 1: qkv (grid 8*16*18), attn, proj (grid 8*16*6), ln
    gemm_bs<2><<<dim3(2304), dim3(256), 0, stream>>>(
        xb, W1, qkv1, bias1, nullptr, nullptr, 1152, 384, 0);
    attn<<<dim3(4, 6, 64), dim3(256), 0, stream>>>(
        qkv1, 1152, qkv1 + 384, 1152, qkv1 + 768, 1152, att);
    gemm_bs<2><<<dim3(768), dim3(256), 0, stream>>>(
        att, pw1t, tmp, s1pb, nullptr, x, 384, 384, 0);
    lnorm<<<dim3(4096), dim3(256), 0, stream>>>(tmp, g1, be1, o1b, nullptr);

    // stage 2 (q2 + kv2 fused: grid 8*16*18)
    gemm_bs_dual<<<dim3(2304), dim3(256), 0, stream>>>(
        o1b, W2, q2, bias2, 384,
        encb, W2 + 147456, kv2, bias2 + 384, 768, 6);
    attn<<<dim3(4, 6, 64), dim3(256), 0, stream>>>(
        q2, 384, kv2, 768, kv2 + 384, 768, att);
    gemm_bs<2><<<dim3(768), dim3(256), 0, stream>>>(
        att, pw2t, tmp, s2pb, o1b, nullptr, 384, 384, 0);
    lnorm<<<dim3(4096), dim3(256), 0, stream>>>(tmp, g2, be2, o2b, nullptr);

    // stage 3: ffn1 (grid 8*16*24), ffn2 (grid 8*16*6, K=1536 -> 12 chunks)
    gemm_bs<2><<<dim3(3072), dim3(256), 0, stream>>>(
        o2b, w1t, h1, fb1, nullptr, nullptr, 1536, 384, 1);
    gemm_bs<2><<<dim3(768), dim3(256), 0, stream>>>(
        h1, w2t, tmp, fb2, o2b, nullptr, 384, 1536, 0);
    lnorm<<<dim3(4096), dim3(256), 0, stream>>>(tmp, g3, be3, nullptr, (float*)d_out);
}